// Round 6
// baseline (94.503 us; speedup 1.0000x reference)
//
#include <hip/hip_runtime.h>

// Problem constants (fixed by the reference)
#define B_ 512
#define T_ 256
#define C_ 384
#define H_ 64
#define WT_STRIDE (H_ * C_)   // 24576 elements per matrix in WT scratch

typedef __bf16 bf16;
typedef bf16  bf16x8 __attribute__((ext_vector_type(8)));
typedef float f32x4  __attribute__((ext_vector_type(4)));

// ---------------- prep: W (fp32 [C][H]) -> WT (bf16 [mat][h][k]) ----------------
__global__ void prep_wt(const float* __restrict__ Wq,
                        const float* __restrict__ Wk,
                        const float* __restrict__ Wv,
                        bf16* __restrict__ wt)
{
    int idx = blockIdx.x * 256 + threadIdx.x;
    if (idx >= 3 * WT_STRIDE) return;
    int mat = idx / WT_STRIDE;
    int r   = idx % WT_STRIDE;
    int h   = r / C_;
    int k   = r % C_;
    const float* W = (mat == 0) ? Wq : (mat == 1) ? Wk : Wv;
    wt[idx] = (bf16)W[k * H_ + h];
}

__device__ __forceinline__ bf16x8 cvt8(float4 a, float4 b)
{
    bf16x8 r;
    r[0] = (bf16)a.x; r[1] = (bf16)a.y; r[2] = (bf16)a.z; r[3] = (bf16)a.w;
    r[4] = (bf16)b.x; r[5] = (bf16)b.y; r[6] = (bf16)b.z; r[7] = (bf16)b.w;
    return r;
}

// XOR swizzle for k_s / vT_s / p_s: permute 8-elem (16B) chunks within a row.
#define SWZ(row, col) ((col) ^ (((row) & 7) << 3))

// wt_s fragment address: [mc = mat*64+col][kk 0..191] bf16, byte-swizzled.
__device__ __forceinline__ const bf16x8* wts_frag(const bf16* wt_s, int mc, int kk)
{
    int byte = ((mc * 192 + kk) * 2) ^ ((mc & 7) << 4);
    return reinterpret_cast<const bf16x8*>(reinterpret_cast<const char*>(wt_s) + byte);
}

template<int USE_WT>
__global__ __launch_bounds__(512, 1)   // 1 block/CU (LDS 152KB); VGPR cap 256 is free at 8 waves/CU
void head_fused6(const float* __restrict__ x,
                 const float* __restrict__ Wq,
                 const float* __restrict__ Wk,
                 const float* __restrict__ Wv,
                 const bf16* __restrict__ wt,
                 float* __restrict__ out)
{
    // 73728 + 32768 + 32768 + 16384 = 155648 B <= 160 KiB (1 block/CU)
    __shared__ bf16 wt_s[3 * 64 * 192];  // [mat*64+col][kk] half-K of all 3 mats
    __shared__ bf16 k_s[T_ * 64];        // [t=256][h=64]  swizzled
    __shared__ bf16 vT_s[H_ * 256];      // [h=64][t=256]  swizzled
    __shared__ bf16 p_s[8 * 16 * 64];    // per-wave bounce (q then P), swizzled

    const int tid  = threadIdx.x;
    const int wave = tid >> 6;
    const int lane = tid & 63;
    const int lr   = lane & 15;
    const int lg   = lane >> 4;

    const int b = blockIdx.x;
    const float* xb = x + (size_t)b * T_ * C_;
    bf16* pw = &p_s[wave * 16 * 64];

    bf16x8 qf[2][2];       // q A-fragments for this wave's two q-tiles
    bf16x8 af[2][2][6];    // x A-fragments [half][tile][ks] — loaded once

    // ---- load ALL x for this wave's two tiles (4 batches of 12 float4) ----
    #pragma unroll
    for (int half = 0; half < 2; ++half) {
        #pragma unroll
        for (int tile = 0; tile < 2; ++tile) {
            const int mt = tile ? (15 - wave) : wave;
            const float* xrow = xb + (mt * 16 + lr) * C_ + half * 192 + lg * 8;
            float4 t0[6], t1[6];
            #pragma unroll
            for (int ks = 0; ks < 6; ++ks) {
                t0[ks] = *reinterpret_cast<const float4*>(xrow + ks * 32);
                t1[ks] = *reinterpret_cast<const float4*>(xrow + ks * 32 + 4);
            }
            #pragma unroll
            for (int ks = 0; ks < 6; ++ks)
                af[half][tile][ks] = cvt8(t0[ks], t1[ks]);
        }
    }

    // ---------------- Phase 1: q,k,v projections, BOTH tiles at once ----------------
    // B-fragments (WT) are tile-independent: read once, feed 2 MFMAs (halved LDS traffic).
    f32x4 acc[2][3][4];   // [tile][q,k,v][nw]
    #pragma unroll
    for (int tile = 0; tile < 2; ++tile)
        #pragma unroll
        for (int a = 0; a < 3; ++a)
            #pragma unroll
            for (int nw = 0; nw < 4; ++nw)
                acc[tile][a][nw] = (f32x4){0.f, 0.f, 0.f, 0.f};

    #pragma unroll
    for (int half = 0; half < 2; ++half) {
        if (half) __syncthreads();   // previous wt_s consumers done
        // ---- stage wt_s: 4608 16B chunks over 512 threads = 9 each ----
        if (USE_WT) {
            bf16x8 v[9];
            #pragma unroll
            for (int c = 0; c < 9; ++c) {   // batched loads
                int f16 = c * 512 + tid;    // chunk idx; f16 = mc*24 + kkc
                int mc  = f16 / 24;
                int kkc = f16 % 24;
                v[c] = *reinterpret_cast<const bf16x8*>(
                    wt + mc * 384 + half * 192 + kkc * 8);
            }
            #pragma unroll
            for (int c = 0; c < 9; ++c) {
                int f16 = c * 512 + tid;
                int mc  = f16 / 24;
                int kkc = f16 % 24;
                int byte = ((mc * 192 + kkc * 8) * 2) ^ ((mc & 7) << 4);
                *reinterpret_cast<bf16x8*>(reinterpret_cast<char*>(wt_s) + byte) = v[c];
            }
        } else {
            #pragma unroll
            for (int c = 0; c < 9; ++c) {
                int f16 = c * 512 + tid;
                int mc  = f16 / 24;
                int kkc = f16 % 24;
                int mat = mc >> 6, col = mc & 63;
                const float* W = (mat == 0) ? Wq : (mat == 1) ? Wk : Wv;
                bf16x8 vv;
                #pragma unroll
                for (int j = 0; j < 8; ++j)
                    vv[j] = (bf16)W[(half * 192 + kkc * 8 + j) * H_ + col];
                int byte = ((mc * 192 + kkc * 8) * 2) ^ ((mc & 7) << 4);
                *reinterpret_cast<bf16x8*>(reinterpret_cast<char*>(wt_s) + byte) = vv;
            }
        }
        __syncthreads();   // wt_s ready

        // ---- consume: each B-frag read feeds both tiles' MFMAs ----
        #pragma unroll
        for (int ks = 0; ks < 6; ++ks) {
            const int kk = ks * 32 + lg * 8;
            #pragma unroll
            for (int mat = 0; mat < 3; ++mat) {
                #pragma unroll
                for (int nw = 0; nw < 4; ++nw) {
                    bf16x8 bfr = *wts_frag(wt_s, mat * 64 + nw * 16 + lr, kk);
                    acc[0][mat][nw] = __builtin_amdgcn_mfma_f32_16x16x32_bf16(
                        af[half][0][ks], bfr, acc[0][mat][nw], 0, 0, 0);
                    acc[1][mat][nw] = __builtin_amdgcn_mfma_f32_16x16x32_bf16(
                        af[half][1][ks], bfr, acc[1][mat][nw], 0, 0, 0);
                }
            }
        }
    }

    // ---- epilogue: k/vT to LDS, q through per-wave bounce to A-frags ----
    #pragma unroll
    for (int tile = 0; tile < 2; ++tile) {
        const int mt = tile ? (15 - wave) : wave;
        #pragma unroll
        for (int nw = 0; nw < 4; ++nw) {
            #pragma unroll
            for (int r = 0; r < 4; ++r) {
                int row = mt * 16 + lg * 4 + r;   // t
                int col = nw * 16 + lr;           // h
                k_s[row * 64 + SWZ(row, col)]   = (bf16)acc[tile][1][nw][r];
                vT_s[col * 256 + SWZ(col, row)] = (bf16)acc[tile][2][nw][r];
            }
        }
        #pragma unroll
        for (int nw = 0; nw < 4; ++nw) {
            #pragma unroll
            for (int r = 0; r < 4; ++r) {
                int row = lg * 4 + r;
                pw[row * 64 + SWZ(row, nw * 16 + lr)] = (bf16)acc[tile][0][nw][r];
            }
        }
        asm volatile("s_waitcnt lgkmcnt(0)" ::: "memory");
        __builtin_amdgcn_sched_barrier(0);
        qf[tile][0] = *reinterpret_cast<const bf16x8*>(&pw[lr * 64 + SWZ(lr, lg * 8)]);
        qf[tile][1] = *reinterpret_cast<const bf16x8*>(&pw[lr * 64 + SWZ(lr, 32 + lg * 8)]);
        // reads must land before the next tile's bounce writes overwrite pw
        asm volatile("s_waitcnt lgkmcnt(0)" ::: "memory");
        __builtin_amdgcn_sched_barrier(0);
    }
    __syncthreads();   // k_s / vT_s complete

    // ---------------- Phase 2: causal attention, flash-style two halves ----------------
    const float scale = 0.051031036307982884f;   // 384^-0.5 (C, not H)

    #pragma unroll
    for (int p = 0; p < 2; ++p) {
        const int mt  = p ? (15 - wave) : wave;
        const int nkt = mt + 1;                   // valid key tiles

        float m[4], l[4];
        f32x4 oacc[4];
        #pragma unroll
        for (int r = 0; r < 4; ++r) { m[r] = -1e30f; l[r] = 0.f; }
        #pragma unroll
        for (int n = 0; n < 4; ++n) oacc[n] = (f32x4){0.f, 0.f, 0.f, 0.f};

        #pragma unroll
        for (int h = 0; h < 2; ++h) {
            const int vh = (nkt - h * 8) < 8 ? (nkt - h * 8) : 8;   // valid tiles in half
            if (vh > 0) {   // wave-uniform
                float s[8][4];
                #pragma unroll
                for (int j = 0; j < 8; ++j) {
                    const int kt = h * 8 + j;
                    if (j < vh) {   // wave-uniform
                        bf16x8 kf0 = *reinterpret_cast<const bf16x8*>(
                            &k_s[(kt * 16 + lr) * 64 + SWZ(lr, lg * 8)]);
                        bf16x8 kf1 = *reinterpret_cast<const bf16x8*>(
                            &k_s[(kt * 16 + lr) * 64 + SWZ(lr, 32 + lg * 8)]);
                        f32x4 sc = (f32x4){0.f, 0.f, 0.f, 0.f};
                        sc = __builtin_amdgcn_mfma_f32_16x16x32_bf16(qf[p][0], kf0, sc, 0, 0, 0);
                        sc = __builtin_amdgcn_mfma_f32_16x16x32_bf16(qf[p][1], kf1, sc, 0, 0, 0);
                        #pragma unroll
                        for (int r = 0; r < 4; ++r) {
                            float v = sc[r] * scale;
                            if (kt == mt && lr > lg * 4 + r) v = -1e30f;   // causal diag
                            s[j][r] = v;
                        }
                    } else {
                        #pragma unroll
                        for (int r = 0; r < 4; ++r) s[j][r] = -1e30f;
                    }
                }

                // per-row max of this half (row lg*4+r spans the 16 lanes of the group)
                float f[4];
                #pragma unroll
                for (int r = 0; r < 4; ++r) {
                    float pm = s[0][r];
                    #pragma unroll
                    for (int j = 1; j < 8; ++j) pm = fmaxf(pm, s[j][r]);
                    pm = fmaxf(pm, __shfl_xor(pm, 1));
                    pm = fmaxf(pm, __shfl_xor(pm, 2));
                    pm = fmaxf(pm, __shfl_xor(pm, 4));
                    pm = fmaxf(pm, __shfl_xor(pm, 8));
                    float nm = fmaxf(m[r], pm);
                    f[r] = __expf(m[r] - nm);   // rescale factor
                    m[r] = nm;
                    l[r] *= f[r];
                }
                #pragma unroll
                for (int n = 0; n < 4; ++n)
                    #pragma unroll
                    for (int r = 0; r < 4; ++r)
                        oacc[n][r] *= f[r];

                // exp + row sum
                #pragma unroll
                for (int r = 0; r < 4; ++r) {
                    float t = 0.f;
                    #pragma unroll
                    for (int j = 0; j < 8; ++j) {
                        float e = __expf(s[j][r] - m[r]);
                        s[j][r] = e;
                        t += e;
                    }
                    t += __shfl_xor(t, 1);
                    t += __shfl_xor(t, 2);
                    t += __shfl_xor(t, 4);
                    t += __shfl_xor(t, 8);
                    l[r] += t;
                }

                // PV (unnormalized P through the bounce)
                const int nkk = (vh + 1) >> 1;
                #pragma unroll
                for (int kkl = 0; kkl < 4; ++kkl) {
                    if (kkl < nkk) {   // wave-uniform
                        const int kk = h * 4 + kkl;
                        #pragma unroll
                        for (int r = 0; r < 4; ++r) {
                            int row = lg * 4 + r;
                            pw[row * 64 + SWZ(row, lr)]      = (bf16)s[2 * kkl][r];
                            pw[row * 64 + SWZ(row, 16 + lr)] = (bf16)s[2 * kkl + 1][r];
                        }
                        asm volatile("s_waitcnt lgkmcnt(0)" ::: "memory");
                        __builtin_amdgcn_sched_barrier(0);
                        bf16x8 pf = *reinterpret_cast<const bf16x8*>(
                            &pw[lr * 64 + SWZ(lr, lg * 8)]);
                        #pragma unroll
                        for (int n = 0; n < 4; ++n) {
                            bf16x8 vf = *reinterpret_cast<const bf16x8*>(
                                &vT_s[(n * 16 + lr) * 256 + SWZ(lr, kk * 32 + lg * 8)]);
                            oacc[n] = __builtin_amdgcn_mfma_f32_16x16x32_bf16(pf, vf, oacc[n], 0, 0, 0);
                        }
                    }
                }
            }
        }

        // epilogue: normalize by 1/l and store
        float rin[4];
        #pragma unroll
        for (int r = 0; r < 4; ++r) rin[r] = 1.0f / l[r];
        float* op = out + ((size_t)b * T_ + mt * 16) * H_;
        #pragma unroll
        for (int n = 0; n < 4; ++n)
            #pragma unroll
            for (int r = 0; r < 4; ++r)
                op[(lg * 4 + r) * H_ + n * 16 + lr] = oacc[n][r] * rin[r];
    }
}

extern "C" void kernel_launch(void* const* d_in, const int* in_sizes, int n_in,
                              void* d_out, int out_size, void* d_ws, size_t ws_size,
                              hipStream_t stream)
{
    (void)in_sizes; (void)n_in; (void)out_size;
    const float* x  = (const float*)d_in[0];
    const float* Wq = (const float*)d_in[1];
    const float* Wk = (const float*)d_in[2];
    const float* Wv = (const float*)d_in[3];
    float* o = (float*)d_out;

    if (ws_size >= (size_t)(3 * WT_STRIDE * sizeof(bf16))) {
        bf16* wt = (bf16*)d_ws;
        prep_wt<<<dim3((3 * WT_STRIDE + 255) / 256), dim3(256), 0, stream>>>(Wq, Wk, Wv, wt);
        head_fused6<1><<<dim3(B_), dim3(512), 0, stream>>>(x, Wq, Wk, Wv, wt, o);
    } else {
        head_fused6<0><<<dim3(B_), dim3(512), 0, stream>>>(x, Wq, Wk, Wv, nullptr, o);
    }
}

// Round 7
// 78.116 us; speedup vs baseline: 1.2098x; 1.2098x over previous
//
#include <hip/hip_runtime.h>

// Problem constants (fixed by the reference)
#define B_ 512
#define T_ 256
#define C_ 384
#define H_ 64
#define WT2_HALF  36864              // elems per K-half in staged-order wt2
#define WT2_TOTAL (2 * WT2_HALF)     // 73728 elems = 147456 B

typedef __bf16 bf16;
typedef bf16  bf16x8 __attribute__((ext_vector_type(8)));
typedef float f32x4  __attribute__((ext_vector_type(4)));

// ---------------- prep: W (fp32 [C][H]) -> wt2 (bf16, STAGING order) ----------------
// Kernel stages wt_s with global_load_lds (linear LDS dest). To end up with the
// swizzled wt_s layout, wt2 holds chunks in slot order s = mc*24 + (kkc^(mc&7)),
// so a linear copy of wt2 produces the swizzled LDS image (pre-swizzled-source).
__global__ void prep_wt2(const float* __restrict__ Wq,
                         const float* __restrict__ Wk,
                         const float* __restrict__ Wv,
                         bf16* __restrict__ wt2)
{
    int idx = blockIdx.x * 256 + threadIdx.x;
    if (idx >= WT2_TOTAL) return;
    int half = idx / WT2_HALF;
    int rem  = idx % WT2_HALF;
    int s    = rem >> 3;             // 16B chunk slot
    int e    = rem & 7;
    int mc   = s / 24;               // mat*64 + col
    int kkc  = (s % 24) ^ (mc & 7);  // inverse of slot swizzle
    int mat  = mc >> 6;
    int col  = mc & 63;
    int k    = half * 192 + kkc * 8 + e;
    const float* W = (mat == 0) ? Wq : (mat == 1) ? Wk : Wv;
    wt2[idx] = (bf16)W[k * H_ + col];
}

__device__ __forceinline__ bf16x8 cvt8(float4 a, float4 b)
{
    bf16x8 r;
    r[0] = (bf16)a.x; r[1] = (bf16)a.y; r[2] = (bf16)a.z; r[3] = (bf16)a.w;
    r[4] = (bf16)b.x; r[5] = (bf16)b.y; r[6] = (bf16)b.z; r[7] = (bf16)b.w;
    return r;
}

// direct HBM/L2 -> LDS, 16B per lane, wave-uniform LDS base + lane*16
__device__ __forceinline__ void gload_lds16(const bf16* g, bf16* l)
{
    __builtin_amdgcn_global_load_lds(
        (const __attribute__((address_space(1))) void*)g,
        (__attribute__((address_space(3))) void*)l,
        16, 0, 0);
}

// XOR swizzle for k_s / vT_s / p_s: permute 8-elem (16B) chunks within a row.
#define SWZ(row, col) ((col) ^ (((row) & 7) << 3))

// wt_s fragment address: [mc = mat*64+col][kk 0..191] bf16, 16B-chunk swizzled.
// Read bank check: bank group = ((ks*4+lg) ^ (lr&7)) -> 8 lanes per 4-bank group
// = perfectly uniform (minimum service time, conflict-free).
__device__ __forceinline__ const bf16x8* wts_frag(const bf16* wt_s, int mc, int kk)
{
    int byte = ((mc * 192 + kk) * 2) ^ ((mc & 7) << 4);
    return reinterpret_cast<const bf16x8*>(reinterpret_cast<const char*>(wt_s) + byte);
}

template<int USE_WT>
__global__
__attribute__((amdgpu_flat_work_group_size(512, 512)))
__attribute__((amdgpu_waves_per_eu(2, 2)))   // LDS caps at 2 waves/SIMD anyway -> take the full 256-VGPR budget
void head_fused7(const float* __restrict__ x,
                 const float* __restrict__ Wq,
                 const float* __restrict__ Wk,
                 const float* __restrict__ Wv,
                 const bf16* __restrict__ wt2,
                 float* __restrict__ out)
{
    // 73728 + 32768 + 32768 + 16384 = 155648 B <= 160 KiB (1 block/CU)
    __shared__ bf16 wt_s[3 * 64 * 192];  // [mat*64+col][kk] one K-half of all 3 mats
    __shared__ bf16 k_s[T_ * 64];        // [t=256][h=64]  swizzled
    __shared__ bf16 vT_s[H_ * 256];      // [h=64][t=256]  swizzled
    __shared__ bf16 p_s[8 * 16 * 64];    // per-wave bounce (q then P), swizzled

    const int tid  = threadIdx.x;
    const int wave = tid >> 6;
    const int lane = tid & 63;
    const int lr   = lane & 15;
    const int lg   = lane >> 4;

    const int b = blockIdx.x;
    const float* xb = x + (size_t)b * T_ * C_;
    bf16* pw = &p_s[wave * 16 * 64];

    const int mt0 = wave;        // this wave's two row tiles (q and k/v rows)
    const int mt1 = 15 - wave;

    bf16x8 qf[2][2];   // q A-fragments, kept in regs for phase 2

    // ---------------- Phase 1: q,k,v projections, both tiles per B-frag read ----------------
    f32x4 acc[2][3][4];   // [tile][q,k,v][nw] — 96 VGPRs, live across halves
    #pragma unroll
    for (int t = 0; t < 2; ++t)
        #pragma unroll
        for (int a = 0; a < 3; ++a)
            #pragma unroll
            for (int nw = 0; nw < 4; ++nw)
                acc[t][a][nw] = (f32x4){0.f, 0.f, 0.f, 0.f};

    #pragma unroll 1
    for (int half = 0; half < 2; ++half) {
        __syncthreads();   // previous wt_s consumers done
        // ---- stage wt_s: 4608 16B chunks; 9 direct global->LDS per wave ----
        if (USE_WT) {
            #pragma unroll
            for (int c = 0; c < 9; ++c) {
                const bf16* g = wt2 + half * WT2_HALF + (c * 512 + tid) * 8;
                bf16* l = wt_s + (c * 512 + wave * 64) * 8;   // linear dest
                gload_lds16(g, l);
            }
        } else {
            // fallback: gather from fp32 W, manual swizzled ds_write
            #pragma unroll
            for (int c = 0; c < 9; ++c) {
                int f16 = c * 512 + tid;
                int mc  = f16 / 24;
                int kkc = f16 % 24;
                int mat = mc >> 6, col = mc & 63;
                const float* W = (mat == 0) ? Wq : (mat == 1) ? Wk : Wv;
                bf16x8 vv;
                #pragma unroll
                for (int j = 0; j < 8; ++j)
                    vv[j] = (bf16)W[(half * 192 + kkc * 8 + j) * H_ + col];
                int byte = ((mc * 192 + kkc * 8) * 2) ^ ((mc & 7) << 4);
                *reinterpret_cast<bf16x8*>(reinterpret_cast<char*>(wt_s) + byte) = vv;
            }
        }

        // ---- x for this half, both tiles (overlaps with staging) ----
        bf16x8 af0[6], af1[6];
        {
            const float* xr = xb + (mt0 * 16 + lr) * C_ + half * 192 + lg * 8;
            float4 t0[6], t1[6];
            #pragma unroll
            for (int ks = 0; ks < 6; ++ks) {
                t0[ks] = *reinterpret_cast<const float4*>(xr + ks * 32);
                t1[ks] = *reinterpret_cast<const float4*>(xr + ks * 32 + 4);
            }
            #pragma unroll
            for (int ks = 0; ks < 6; ++ks) af0[ks] = cvt8(t0[ks], t1[ks]);
        }
        {
            const float* xr = xb + (mt1 * 16 + lr) * C_ + half * 192 + lg * 8;
            float4 t0[6], t1[6];
            #pragma unroll
            for (int ks = 0; ks < 6; ++ks) {
                t0[ks] = *reinterpret_cast<const float4*>(xr + ks * 32);
                t1[ks] = *reinterpret_cast<const float4*>(xr + ks * 32 + 4);
            }
            #pragma unroll
            for (int ks = 0; ks < 6; ++ks) af1[ks] = cvt8(t0[ks], t1[ks]);
        }
        __syncthreads();   // wt_s ready (drains vmcnt incl. global_load_lds)

        // ---- consume: each B-frag read feeds BOTH tiles (halved LDS traffic) ----
        #pragma unroll
        for (int ks = 0; ks < 6; ++ks) {
            const int kk = ks * 32 + lg * 8;
            #pragma unroll
            for (int mat = 0; mat < 3; ++mat) {
                #pragma unroll
                for (int nw = 0; nw < 4; ++nw) {
                    bf16x8 bfr = *wts_frag(wt_s, mat * 64 + nw * 16 + lr, kk);
                    acc[0][mat][nw] = __builtin_amdgcn_mfma_f32_16x16x32_bf16(
                        af0[ks], bfr, acc[0][mat][nw], 0, 0, 0);
                    acc[1][mat][nw] = __builtin_amdgcn_mfma_f32_16x16x32_bf16(
                        af1[ks], bfr, acc[1][mat][nw], 0, 0, 0);
                }
            }
        }
    }

    // ---- epilogue: k/vT to LDS, q through per-wave bounce to A-frags ----
    #pragma unroll
    for (int tile = 0; tile < 2; ++tile) {
        const int mt = tile ? mt1 : mt0;
        #pragma unroll
        for (int nw = 0; nw < 4; ++nw) {
            #pragma unroll
            for (int r = 0; r < 4; ++r) {
                int row = mt * 16 + lg * 4 + r;   // t
                int col = nw * 16 + lr;           // h
                k_s[row * 64 + SWZ(row, col)]   = (bf16)acc[tile][1][nw][r];
                vT_s[col * 256 + SWZ(col, row)] = (bf16)acc[tile][2][nw][r];
            }
        }
        #pragma unroll
        for (int nw = 0; nw < 4; ++nw) {
            #pragma unroll
            for (int r = 0; r < 4; ++r) {
                int row = lg * 4 + r;
                pw[row * 64 + SWZ(row, nw * 16 + lr)] = (bf16)acc[tile][0][nw][r];
            }
        }
        asm volatile("s_waitcnt lgkmcnt(0)" ::: "memory");
        __builtin_amdgcn_sched_barrier(0);
        qf[tile][0] = *reinterpret_cast<const bf16x8*>(&pw[lr * 64 + SWZ(lr, lg * 8)]);
        qf[tile][1] = *reinterpret_cast<const bf16x8*>(&pw[lr * 64 + SWZ(lr, 32 + lg * 8)]);
        // next tile's pw writes are same-wave DS ops -> in-order, no extra drain needed
    }
    __syncthreads();   // k_s / vT_s complete

    // ---------------- Phase 2: causal attention, flash-style two halves ----------------
    const float scale = 0.051031036307982884f;   // 384^-0.5 (C, not H)

    #pragma unroll
    for (int p = 0; p < 2; ++p) {
        const int mt  = p ? mt1 : mt0;
        const int nkt = mt + 1;                   // valid key tiles

        float m[4], l[4];
        f32x4 oacc[4];
        #pragma unroll
        for (int r = 0; r < 4; ++r) { m[r] = -1e30f; l[r] = 0.f; }
        #pragma unroll
        for (int n = 0; n < 4; ++n) oacc[n] = (f32x4){0.f, 0.f, 0.f, 0.f};

        #pragma unroll
        for (int h = 0; h < 2; ++h) {
            const int vh = (nkt - h * 8) < 8 ? (nkt - h * 8) : 8;   // valid tiles in half
            if (vh > 0) {   // wave-uniform
                float s[8][4];
                #pragma unroll
                for (int j = 0; j < 8; ++j) {
                    const int kt = h * 8 + j;
                    if (j < vh) {   // wave-uniform
                        bf16x8 kf0 = *reinterpret_cast<const bf16x8*>(
                            &k_s[(kt * 16 + lr) * 64 + SWZ(lr, lg * 8)]);
                        bf16x8 kf1 = *reinterpret_cast<const bf16x8*>(
                            &k_s[(kt * 16 + lr) * 64 + SWZ(lr, 32 + lg * 8)]);
                        f32x4 sc = (f32x4){0.f, 0.f, 0.f, 0.f};
                        sc = __builtin_amdgcn_mfma_f32_16x16x32_bf16(qf[p][0], kf0, sc, 0, 0, 0);
                        sc = __builtin_amdgcn_mfma_f32_16x16x32_bf16(qf[p][1], kf1, sc, 0, 0, 0);
                        #pragma unroll
                        for (int r = 0; r < 4; ++r) {
                            float v = sc[r] * scale;
                            if (kt == mt && lr > lg * 4 + r) v = -1e30f;   // causal diag
                            s[j][r] = v;
                        }
                    } else {
                        #pragma unroll
                        for (int r = 0; r < 4; ++r) s[j][r] = -1e30f;
                    }
                }

                // per-row max of this half (row lg*4+r spans the 16 lanes of the group)
                float f[4];
                #pragma unroll
                for (int r = 0; r < 4; ++r) {
                    float pm = s[0][r];
                    #pragma unroll
                    for (int j = 1; j < 8; ++j) pm = fmaxf(pm, s[j][r]);
                    pm = fmaxf(pm, __shfl_xor(pm, 1));
                    pm = fmaxf(pm, __shfl_xor(pm, 2));
                    pm = fmaxf(pm, __shfl_xor(pm, 4));
                    pm = fmaxf(pm, __shfl_xor(pm, 8));
                    float nm = fmaxf(m[r], pm);
                    f[r] = __expf(m[r] - nm);   // rescale factor
                    m[r] = nm;
                    l[r] *= f[r];
                }
                #pragma unroll
                for (int n = 0; n < 4; ++n)
                    #pragma unroll
                    for (int r = 0; r < 4; ++r)
                        oacc[n][r] *= f[r];

                // exp + row sum
                #pragma unroll
                for (int r = 0; r < 4; ++r) {
                    float t = 0.f;
                    #pragma unroll
                    for (int j = 0; j < 8; ++j) {
                        float e = __expf(s[j][r] - m[r]);
                        s[j][r] = e;
                        t += e;
                    }
                    t += __shfl_xor(t, 1);
                    t += __shfl_xor(t, 2);
                    t += __shfl_xor(t, 4);
                    t += __shfl_xor(t, 8);
                    l[r] += t;
                }

                // PV (unnormalized P through the bounce)
                const int nkk = (vh + 1) >> 1;
                #pragma unroll
                for (int kkl = 0; kkl < 4; ++kkl) {
                    if (kkl < nkk) {   // wave-uniform
                        const int kk = h * 4 + kkl;
                        #pragma unroll
                        for (int r = 0; r < 4; ++r) {
                            int row = lg * 4 + r;
                            pw[row * 64 + SWZ(row, lr)]      = (bf16)s[2 * kkl][r];
                            pw[row * 64 + SWZ(row, 16 + lr)] = (bf16)s[2 * kkl + 1][r];
                        }
                        asm volatile("s_waitcnt lgkmcnt(0)" ::: "memory");
                        __builtin_amdgcn_sched_barrier(0);
                        bf16x8 pf = *reinterpret_cast<const bf16x8*>(
                            &pw[lr * 64 + SWZ(lr, lg * 8)]);
                        #pragma unroll
                        for (int n = 0; n < 4; ++n) {
                            bf16x8 vf = *reinterpret_cast<const bf16x8*>(
                                &vT_s[(n * 16 + lr) * 256 + SWZ(lr, kk * 32 + lg * 8)]);
                            oacc[n] = __builtin_amdgcn_mfma_f32_16x16x32_bf16(pf, vf, oacc[n], 0, 0, 0);
                        }
                    }
                }
            }
        }

        // epilogue: normalize by 1/l and store
        float rin[4];
        #pragma unroll
        for (int r = 0; r < 4; ++r) rin[r] = 1.0f / l[r];
        float* op = out + ((size_t)b * T_ + mt * 16) * H_;
        #pragma unroll
        for (int n = 0; n < 4; ++n)
            #pragma unroll
            for (int r = 0; r < 4; ++r)
                op[(lg * 4 + r) * H_ + n * 16 + lr] = oacc[n][r] * rin[r];
    }
}

extern "C" void kernel_launch(void* const* d_in, const int* in_sizes, int n_in,
                              void* d_out, int out_size, void* d_ws, size_t ws_size,
                              hipStream_t stream)
{
    (void)in_sizes; (void)n_in; (void)out_size;
    const float* x  = (const float*)d_in[0];
    const float* Wq = (const float*)d_in[1];
    const float* Wk = (const float*)d_in[2];
    const float* Wv = (const float*)d_in[3];
    float* o = (float*)d_out;

    if (ws_size >= (size_t)(WT2_TOTAL * sizeof(bf16))) {
        bf16* wt2 = (bf16*)d_ws;
        prep_wt2<<<dim3((WT2_TOTAL + 255) / 256), dim3(256), 0, stream>>>(Wq, Wk, Wv, wt2);
        head_fused7<1><<<dim3(B_), dim3(512), 0, stream>>>(x, Wq, Wk, Wv, wt2, o);
    } else {
        head_fused7<0><<<dim3(B_), dim3(512), 0, stream>>>(x, Wq, Wk, Wv, nullptr, o);
    }
}